// Round 4
// baseline (387.277 us; speedup 1.0000x reference)
//
#include <hip/hip_runtime.h>

#define SCALE 0.125f

typedef short short8 __attribute__((ext_vector_type(8)));
typedef float f32x4 __attribute__((ext_vector_type(4)));
typedef unsigned short us8 __attribute__((ext_vector_type(8)));

__device__ __forceinline__ unsigned short f2bf(float x) {
  unsigned int u = __float_as_uint(x);
  u += 0x7fff + ((u >> 16) & 1);
  return (unsigned short)(u >> 16);
}
__device__ __forceinline__ float bf2f(unsigned short b) {
  return __uint_as_float(((unsigned int)b) << 16);
}
__device__ __forceinline__ float gelu_exact(float x) {
  return 0.5f * x * (1.0f + erff(x * 0.70710678118654752f));
}

// ---------------------------------------------------------------------------
// Weight casts f32 -> bf16 (concatenated: qkvf | qkvp | fc1w | fc2w)
// ---------------------------------------------------------------------------
__global__ __launch_bounds__(256)
void cast_w(const float* __restrict__ qf, const float* __restrict__ qp,
            const float* __restrict__ f1, const float* __restrict__ f2,
            unsigned short* __restrict__ wc)
{
  const int i4 = (blockIdx.x * 256 + threadIdx.x) * 4;   // 1179648 total elems
  const float* src; int off;
  if (i4 < 196608)      { src = qf; off = i4; }
  else if (i4 < 393216) { src = qp; off = i4 - 196608; }
  else if (i4 < 917504) { src = f1; off = i4 - 393216; }
  else                  { src = f2; off = i4 - 917504; }
  const float4 v = *(const float4*)(src + off);
  ushort4 o;
  o.x = f2bf(v.x); o.y = f2bf(v.y); o.z = f2bf(v.z); o.w = f2bf(v.w);
  *(ushort4*)(wc + i4) = o;
}

// ---------------------------------------------------------------------------
// xT[z=(path*8+b)][tok 1024][ch 256] = bf16( x[b][path*256+ch][tok] )
// ---------------------------------------------------------------------------
__global__ __launch_bounds__(256)
void trans_x(const float* __restrict__ x, unsigned short* __restrict__ xT)
{
  __shared__ unsigned short L[64 * 72];
  const int ch0 = blockIdx.x * 64, tok0 = blockIdx.y * 64, z = blockIdx.z;
  const int b = z & 7, path = z >> 3;
  const float* src = x + (size_t)b * 524288 + (size_t)(path * 256 + ch0) * 1024 + tok0;
#pragma unroll
  for (int t = 0; t < 4; ++t) {
    const int i = threadIdx.x + t * 256;
    const int row = i >> 4, c4 = (i & 15) * 4;      // row = ch, c4 = tok
    const float4 v = *(const float4*)(src + (size_t)row * 1024 + c4);
    L[(c4 + 0) * 72 + row] = f2bf(v.x);
    L[(c4 + 1) * 72 + row] = f2bf(v.y);
    L[(c4 + 2) * 72 + row] = f2bf(v.z);
    L[(c4 + 3) * 72 + row] = f2bf(v.w);
  }
  __syncthreads();
  unsigned short* dst = xT + (size_t)z * 262144 + (size_t)tok0 * 256 + ch0;
#pragma unroll
  for (int t = 0; t < 2; ++t) {
    const int i = threadIdx.x + t * 256;
    const int row = i >> 3, c8 = (i & 7) * 8;       // row = tok, c8 = ch
    *(us8*)(dst + (size_t)row * 256 + c8) = *(const us8*)&L[row * 72 + c8];
  }
}

// ---------------------------------------------------------------------------
// gbT[which][tok 1024][ch 512] = bf16( {gamma,beta}[ch][tok] )
// ---------------------------------------------------------------------------
__global__ __launch_bounds__(256)
void trans_gb(const float* __restrict__ gamma, const float* __restrict__ beta,
              unsigned short* __restrict__ gbT)
{
  __shared__ unsigned short L[64 * 72];
  const int ch0 = blockIdx.x * 64, tok0 = blockIdx.y * 64, which = blockIdx.z;
  const float* src = (which ? beta : gamma) + (size_t)ch0 * 1024 + tok0;
#pragma unroll
  for (int t = 0; t < 4; ++t) {
    const int i = threadIdx.x + t * 256;
    const int row = i >> 4, c4 = (i & 15) * 4;
    const float4 v = *(const float4*)(src + (size_t)row * 1024 + c4);
    L[(c4 + 0) * 72 + row] = f2bf(v.x);
    L[(c4 + 1) * 72 + row] = f2bf(v.y);
    L[(c4 + 2) * 72 + row] = f2bf(v.z);
    L[(c4 + 3) * 72 + row] = f2bf(v.w);
  }
  __syncthreads();
  unsigned short* dst = gbT + (size_t)which * 524288 + (size_t)tok0 * 512 + ch0;
#pragma unroll
  for (int t = 0; t < 2; ++t) {
    const int i = threadIdx.x + t * 256;
    const int row = i >> 3, c8 = (i & 7) * 8;
    *(us8*)(dst + (size_t)row * 512 + c8) = *(const us8*)&L[row * 72 + c8];
  }
}

// ---------------------------------------------------------------------------
// MFMA GEMM: C[M][N] = A[M][K] @ B[N][K]^T, A/B bf16 k-contiguous.
// 128x128 block tile, 4 waves (2x2) of 64x64. Reg-staged double-buffered LDS,
// one barrier per k32 step. LDS rows unpadded (32 bf16) + XOR chunk swizzle.
// MODE 0: qkv -> qkT[z][tok][512] (m<512, transposed) + vbuf[z][ch][tok]
// MODE 1: fc1 -> bias+gelu -> hT[z][tok][1024] bf16 (transposed)
// MODE 2: fc2 -> bias -> out[z][oc][tok] f32
// ---------------------------------------------------------------------------
template<int MODE, int K>
__global__ __launch_bounds__(256, 3)
void gemm_mf(const unsigned short* __restrict__ A0, const unsigned short* __restrict__ B0,
             unsigned short* __restrict__ qkT, unsigned short* __restrict__ vb,
             unsigned short* __restrict__ hT, float* __restrict__ outF,
             const float* __restrict__ bias)
{
  __shared__ unsigned short As[2][4096];
  __shared__ unsigned short Bs[2][4096];
  const int tid = threadIdx.x;
  const int lane = tid & 63, w = tid >> 6;
  const int c = lane & 15, g = lane >> 4;
  const int wm = w >> 1, wn = w & 1;
  const int m0 = blockIdx.x * 128, n0 = blockIdx.y * 128;
  const int z = blockIdx.z;

  const unsigned short* A;
  const unsigned short* B;
  if (MODE == 0) {
    A = A0 + (size_t)(z >> 3) * 196608;
    B = B0 + (size_t)z * 262144;
  } else {
    A = A0;
    B = B0 + (size_t)z * 1024 * K;
  }

  f32x4 acc[4][4];
#pragma unroll
  for (int mi = 0; mi < 4; ++mi)
#pragma unroll
    for (int ni = 0; ni < 4; ++ni) acc[mi][ni] = (f32x4){0.f, 0.f, 0.f, 0.f};

  us8 a_r[2], b_r[2];
#pragma unroll
  for (int t = 0; t < 2; ++t) {
    const int i = tid + t * 256;
    const int row = i >> 2, kc = (i & 3) * 8;
    a_r[t] = *(const us8*)(A + (size_t)(m0 + row) * K + kc);
    b_r[t] = *(const us8*)(B + (size_t)(n0 + row) * K + kc);
  }

  int buf = 0;
  const int NK = K / 32;
  for (int ks = 0; ks < NK; ++ks) {
#pragma unroll
    for (int t = 0; t < 2; ++t) {
      const int i = tid + t * 256;
      const int row = i >> 2, kc = i & 3;
      const int p = row * 32 + ((kc ^ (row & 3)) * 8);
      *(us8*)&As[buf][p] = a_r[t];
      *(us8*)&Bs[buf][p] = b_r[t];
    }
    __syncthreads();
    if (ks + 1 < NK) {
      const int k0 = (ks + 1) * 32;
#pragma unroll
      for (int t = 0; t < 2; ++t) {
        const int i = tid + t * 256;
        const int row = i >> 2, kc = (i & 3) * 8;
        a_r[t] = *(const us8*)(A + (size_t)(m0 + row) * K + k0 + kc);
        b_r[t] = *(const us8*)(B + (size_t)(n0 + row) * K + k0 + kc);
      }
    }
    short8 aF[4], bF[4];
#pragma unroll
    for (int mi = 0; mi < 4; ++mi) {
      const int row = 64 * wm + 16 * mi + c;
      aF[mi] = *(const short8*)&As[buf][row * 32 + ((g ^ (row & 3)) * 8)];
    }
#pragma unroll
    for (int ni = 0; ni < 4; ++ni) {
      const int row = 64 * wn + 16 * ni + c;
      bF[ni] = *(const short8*)&Bs[buf][row * 32 + ((g ^ (row & 3)) * 8)];
    }
#pragma unroll
    for (int mi = 0; mi < 4; ++mi)
#pragma unroll
      for (int ni = 0; ni < 4; ++ni)
        acc[mi][ni] = __builtin_amdgcn_mfma_f32_16x16x32_bf16(aF[mi], bF[ni], acc[mi][ni], 0, 0, 0);
    buf ^= 1;
  }

  if (MODE == 0) {
#pragma unroll
    for (int mi = 0; mi < 4; ++mi) {
      const int mb = m0 + 64 * wm + 16 * mi + 4 * g;
#pragma unroll
      for (int ni = 0; ni < 4; ++ni) {
        const int n = n0 + 64 * wn + 16 * ni + c;
        if (mb < 512) {
          ushort4 o4;
          o4.x = f2bf(acc[mi][ni][0]); o4.y = f2bf(acc[mi][ni][1]);
          o4.z = f2bf(acc[mi][ni][2]); o4.w = f2bf(acc[mi][ni][3]);
          *(ushort4*)(qkT + (size_t)z * 524288 + (size_t)n * 512 + mb) = o4;
        } else {
#pragma unroll
          for (int r = 0; r < 4; ++r)
            vb[(size_t)z * 262144 + (size_t)(mb - 512 + r) * 1024 + n] = f2bf(acc[mi][ni][r]);
        }
      }
    }
  } else if (MODE == 1) {
#pragma unroll
    for (int mi = 0; mi < 4; ++mi) {
      const int mb = m0 + 64 * wm + 16 * mi + 4 * g;
      const float4 b4 = *(const float4*)(bias + mb);
#pragma unroll
      for (int ni = 0; ni < 4; ++ni) {
        const int n = n0 + 64 * wn + 16 * ni + c;
        ushort4 o4;
        o4.x = f2bf(gelu_exact(acc[mi][ni][0] + b4.x));
        o4.y = f2bf(gelu_exact(acc[mi][ni][1] + b4.y));
        o4.z = f2bf(gelu_exact(acc[mi][ni][2] + b4.z));
        o4.w = f2bf(gelu_exact(acc[mi][ni][3] + b4.w));
        *(ushort4*)(hT + (size_t)z * 1048576 + (size_t)n * 1024 + mb) = o4;
      }
    }
  } else {
#pragma unroll
    for (int mi = 0; mi < 4; ++mi) {
      const int mb = m0 + 64 * wm + 16 * mi + 4 * g;
      const float4 b4 = *(const float4*)(bias + mb);
#pragma unroll
      for (int ni = 0; ni < 4; ++ni) {
        const int n = n0 + 64 * wn + 16 * ni + c;
        float* op = outF + (size_t)z * 262144 + (size_t)mb * 1024 + n;
        op[0]    = acc[mi][ni][0] + b4.x;
        op[1024] = acc[mi][ni][1] + b4.y;
        op[2048] = acc[mi][ni][2] + b4.z;
        op[3072] = acc[mi][ni][3] + b4.w;
      }
    }
  }
}

// ---------------------------------------------------------------------------
// Barrier-free MFMA flash attention.
// Block = 64 q-rows of one (path,b,head); 4 waves x 16 q-rows; 1024 blocks.
// S computed TRANSPOSED (A=K, B=Q) so each lane owns ONE q-row and
// 4-consecutive-key groups: P packs to 4x ds_write_b64, qh = 2 reads/iter,
// qw = 8 loop-invariant regs. K/V fragments loaded straight from global
// (L1/L2-served, no LDS staging, NO __syncthreads in the main loop).
// Grid: x = pOut*32+bh (stride-64 blocks share K/V -> same XCD), y = q-tile.
// ---------------------------------------------------------------------------
__global__ __launch_bounds__(256, 4)
void attn_k(const unsigned short* __restrict__ qkT,  // [16][1024][512] bf16
            const unsigned short* __restrict__ vbuf, // [16][256][1024] bf16
            const float* __restrict__ hrel,          // [63][64] f32
            const float* __restrict__ wrel,          // [63][64] f32
            unsigned short* __restrict__ xpfT,       // [8][1024][512] bf16
            float* __restrict__ stats)               // [8][2] f32
{
  __shared__ unsigned short lds[64 * 72 + 64 * 68];
  unsigned short* Ps  = lds;            // stride 72: P tile / epilogue Out tile
  unsigned short* QWb = lds;            // prologue overlay, stride 68 (wave-private rows)
  unsigned short* QHb = lds + 64 * 72;  // stride 68

  const int tid = threadIdx.x;
  const int lane = tid & 63, w = tid >> 6;
  const int c = lane & 15, g = lane >> 4;
  const int xb = blockIdx.x;
  const int pOut = xb >> 5, bh = xb & 31;
  const int b = bh >> 2, head = bh & 3, pKV = 1 - pOut;
  const int n0 = blockIdx.y * 64;

  const unsigned short* Qg = qkT + (size_t)(pOut * 8 + b) * 524288 + head * 64;
  const unsigned short* Kg = qkT + (size_t)(pKV * 8 + b) * 524288 + 256 + head * 64;
  const unsigned short* Vg = vbuf + ((size_t)(pKV * 8 + b) * 256 + head * 64) * 1024;

  const int qr = 16 * w + c;                 // this lane's q-row (block-local)
  const short8 aQ0 = *(const short8*)(Qg + (size_t)(n0 + qr) * 512 + 8 * g);
  const short8 aQ1 = *(const short8*)(Qg + (size_t)(n0 + qr) * 512 + 32 + 8 * g);

  // ---- prologue: QW/QH tables via MFMA, frags straight from global f32
#pragma unroll
  for (int f = 0; f < 4; ++f) {
    const int rr = 16 * f + c;
    const int rrc = rr < 63 ? rr : 62;
    const float sc = rr < 63 ? 1.f : 0.f;
    const float4 wa = *(const float4*)(wrel + rrc * 64 + 8 * g);
    const float4 wb = *(const float4*)(wrel + rrc * 64 + 8 * g + 4);
    const float4 wcv = *(const float4*)(wrel + rrc * 64 + 32 + 8 * g);
    const float4 wd = *(const float4*)(wrel + rrc * 64 + 32 + 8 * g + 4);
    const float4 ha = *(const float4*)(hrel + rrc * 64 + 8 * g);
    const float4 hb = *(const float4*)(hrel + rrc * 64 + 8 * g + 4);
    const float4 hc = *(const float4*)(hrel + rrc * 64 + 32 + 8 * g);
    const float4 hd = *(const float4*)(hrel + rrc * 64 + 32 + 8 * g + 4);
    short8 w0, w1, h0, h1;
    w0[0]=f2bf(wa.x*sc); w0[1]=f2bf(wa.y*sc); w0[2]=f2bf(wa.z*sc); w0[3]=f2bf(wa.w*sc);
    w0[4]=f2bf(wb.x*sc); w0[5]=f2bf(wb.y*sc); w0[6]=f2bf(wb.z*sc); w0[7]=f2bf(wb.w*sc);
    w1[0]=f2bf(wcv.x*sc); w1[1]=f2bf(wcv.y*sc); w1[2]=f2bf(wcv.z*sc); w1[3]=f2bf(wcv.w*sc);
    w1[4]=f2bf(wd.x*sc); w1[5]=f2bf(wd.y*sc); w1[6]=f2bf(wd.z*sc); w1[7]=f2bf(wd.w*sc);
    h0[0]=f2bf(ha.x*sc); h0[1]=f2bf(ha.y*sc); h0[2]=f2bf(ha.z*sc); h0[3]=f2bf(ha.w*sc);
    h0[4]=f2bf(hb.x*sc); h0[5]=f2bf(hb.y*sc); h0[6]=f2bf(hb.z*sc); h0[7]=f2bf(hb.w*sc);
    h1[0]=f2bf(hc.x*sc); h1[1]=f2bf(hc.y*sc); h1[2]=f2bf(hc.z*sc); h1[3]=f2bf(hc.w*sc);
    h1[4]=f2bf(hd.x*sc); h1[5]=f2bf(hd.y*sc); h1[6]=f2bf(hd.z*sc); h1[7]=f2bf(hd.w*sc);
    f32x4 zw = {0.f, 0.f, 0.f, 0.f};
    zw = __builtin_amdgcn_mfma_f32_16x16x32_bf16(aQ0, w0, zw, 0, 0, 0);
    zw = __builtin_amdgcn_mfma_f32_16x16x32_bf16(aQ1, w1, zw, 0, 0, 0);
    f32x4 zh = {0.f, 0.f, 0.f, 0.f};
    zh = __builtin_amdgcn_mfma_f32_16x16x32_bf16(aQ0, h0, zh, 0, 0, 0);
    zh = __builtin_amdgcn_mfma_f32_16x16x32_bf16(aQ1, h1, zh, 0, 0, 0);
#pragma unroll
    for (int r = 0; r < 4; ++r) {
      QWb[(16 * w + 4 * g + r) * 68 + 16 * f + c] = f2bf(zw[r]);
      QHb[(16 * w + 4 * g + r) * 68 + 16 * f + c] = f2bf(zh[r]);
    }
  }
  // wave-private rows: no barrier needed before reading own rows back
  const int qa = n0 + qr;
  const int w1i = qa & 31, h1i = qa >> 5;
  float qwv[2][4];
#pragma unroll
  for (int p = 0; p < 2; ++p)
#pragma unroll
    for (int r = 0; r < 4; ++r)
      qwv[p][r] = bf2f(QWb[qr * 68 + 16 * p + 4 * g + r - w1i + 31]);
  const int qhbase = qr * 68 + 31 - h1i;
  __syncthreads();   // QWb(stride 68) rows overlap other waves' Ps(stride 72) rows

  float lsum = 0.f;
  f32x4 O[4];
#pragma unroll
  for (int f = 0; f < 4; ++f) O[f] = (f32x4){0.f, 0.f, 0.f, 0.f};

#pragma unroll 2
  for (int mt = 0; mt < 16; ++mt) {
    const int m0 = mt * 64;
    // V frags (needed last -> issue first), K frags: straight from global
    short8 vB[4][2], kA[4][2];
#pragma unroll
    for (int f = 0; f < 4; ++f) {
      const unsigned short* vp = Vg + (size_t)(16 * f + c) * 1024 + m0 + 8 * g;
      vB[f][0] = *(const short8*)(vp);
      vB[f][1] = *(const short8*)(vp + 32);
      const unsigned short* kp = Kg + (size_t)(m0 + 16 * f + c) * 512 + 8 * g;
      kA[f][0] = *(const short8*)(kp);
      kA[f][1] = *(const short8*)(kp + 32);
    }
    // S^T = K Q^T : rows = keys (16f+4g+r), cols = q-rows (c)
    f32x4 Sf[4];
#pragma unroll
    for (int f = 0; f < 4; ++f) {
      f32x4 z = {0.f, 0.f, 0.f, 0.f};
      z = __builtin_amdgcn_mfma_f32_16x16x32_bf16(kA[f][0], aQ0, z, 0, 0, 0);
      z = __builtin_amdgcn_mfma_f32_16x16x32_bf16(kA[f][1], aQ1, z, 0, 0, 0);
      Sf[f] = z;
    }
    const float qh0 = bf2f(QHb[qhbase + 2 * mt]);
    const float qh1 = bf2f(QHb[qhbase + 2 * mt + 1]);
#pragma unroll
    for (int f = 0; f < 4; ++f) {
      const float qh = (f >= 2) ? qh1 : qh0;
      const float* qwp = qwv[f & 1];
      float p0 = __expf(fmaf(Sf[f][0], SCALE, qh + qwp[0]));
      float p1 = __expf(fmaf(Sf[f][1], SCALE, qh + qwp[1]));
      float p2 = __expf(fmaf(Sf[f][2], SCALE, qh + qwp[2]));
      float p3 = __expf(fmaf(Sf[f][3], SCALE, qh + qwp[3]));
      lsum += (p0 + p1) + (p2 + p3);
      ushort4 pk;
      pk.x = f2bf(p0); pk.y = f2bf(p1); pk.z = f2bf(p2); pk.w = f2bf(p3);
      *(ushort4*)&Ps[qr * 72 + 16 * f + 4 * g] = pk;   // ds_write_b64, 2-way max
    }
    // P row qr is wave-private: in-wave LDS ordering suffices (no barrier)
    const short8 aP0 = *(const short8*)&Ps[qr * 72 + 8 * g];
    const short8 aP1 = *(const short8*)&Ps[qr * 72 + 32 + 8 * g];
#pragma unroll
    for (int f = 0; f < 4; ++f) {
      O[f] = __builtin_amdgcn_mfma_f32_16x16x32_bf16(aP0, vB[f][0], O[f], 0, 0, 0);
      O[f] = __builtin_amdgcn_mfma_f32_16x16x32_bf16(aP1, vB[f][1], O[f], 0, 0, 0);
    }
  }

  // full row-sums: combine the 4 key-groups (lanes differing in g only)
  lsum += __shfl_xor(lsum, 16);
  lsum += __shfl_xor(lsum, 32);
  // O rows are 4g+r -> fetch l from lane (c = 4g+r, g = 0)
  float linv[4];
#pragma unroll
  for (int r = 0; r < 4; ++r) linv[r] = 1.0f / __shfl(lsum, 4 * g + r);

  float o[4][4];
  float ssum = 0.f, ssq = 0.f;
#pragma unroll
  for (int f = 0; f < 4; ++f)
#pragma unroll
    for (int r = 0; r < 4; ++r) {
      const float v = O[f][r] * linv[r];
      o[f][r] = v;
      ssum += v;
      ssq = fmaf(v, v, ssq);
    }
#pragma unroll
  for (int off = 1; off < 64; off <<= 1) {
    ssum += __shfl_xor(ssum, off);
    ssq  += __shfl_xor(ssq, off);
  }
  if (lane == 0) {
    atomicAdd(&stats[b * 2 + 0], ssum);
    atomicAdd(&stats[b * 2 + 1], ssq);
  }

  // stage Out[qrow][d] (wave-private rows), then coalesced global write
#pragma unroll
  for (int f = 0; f < 4; ++f)
#pragma unroll
    for (int r = 0; r < 4; ++r)
      Ps[(16 * w + 4 * g + r) * 72 + 16 * f + c] = f2bf(o[f][r]);
  __syncthreads();
  unsigned short* dst = xpfT + ((size_t)b * 1024 + n0) * 512 + pOut * 256 + head * 64;
#pragma unroll
  for (int t = 0; t < 2; ++t) {
    const int i = tid + t * 256;
    const int row = i >> 3, c8 = (i & 7) * 8;
    *(us8*)(dst + (size_t)row * 512 + c8) = *(const us8*)&Ps[row * 72 + c8];
  }
}

// ---------------------------------------------------------------------------
// LayerNorm apply: xln[b][tok][512] = (xpfT - mean)*rstd*gammaT + betaT (bf16)
// ---------------------------------------------------------------------------
__global__ __launch_bounds__(256)
void ln_k(const unsigned short* __restrict__ xpfT, const unsigned short* __restrict__ gbT,
          const float* __restrict__ stats, unsigned short* __restrict__ xln)
{
  const int i = blockIdx.x * 256 + threadIdx.x;   // us8 chunk index, 524288 total
  const int b = i >> 16, off = i & 65535;
  const float invN = 1.0f / 524288.0f;
  const float mean = stats[b * 2] * invN;
  const float var = stats[b * 2 + 1] * invN - mean * mean;
  const float rstd = rsqrtf(var + 1e-5f);
  const us8 xv = *(const us8*)(xpfT + (size_t)i * 8);
  const us8 gv = *(const us8*)(gbT + (size_t)off * 8);
  const us8 bv = *(const us8*)(gbT + 524288 + (size_t)off * 8);
  us8 ov;
#pragma unroll
  for (int j = 0; j < 8; ++j)
    ov[j] = f2bf((bf2f(xv[j]) - mean) * rstd * bf2f(gv[j]) + bf2f(bv[j]));
  *(us8*)(xln + (size_t)i * 8) = ov;
}

// ---------------------------------------------------------------------------
extern "C" void kernel_launch(void* const* d_in, const int* in_sizes, int n_in,
                              void* d_out, int out_size, void* d_ws, size_t ws_size,
                              hipStream_t stream)
{
  const float* x     = (const float*)d_in[0];
  const float* qkvfw = (const float*)d_in[1];
  const float* qkvpw = (const float*)d_in[2];
  const float* hrel  = (const float*)d_in[3];
  const float* wrel  = (const float*)d_in[4];
  const float* gamma = (const float*)d_in[5];
  const float* beta  = (const float*)d_in[6];
  const float* fc1w  = (const float*)d_in[7];
  const float* fc1b  = (const float*)d_in[8];
  const float* fc2w  = (const float*)d_in[9];
  const float* fc2b  = (const float*)d_in[10];
  float* out = (float*)d_out;

  // ws layout (bf16 elements unless noted), ~63.4 MB total
  float* stats = (float*)d_ws;                                   // 64 f32
  unsigned short* wc   = (unsigned short*)(stats + 64);          // 1179648
  unsigned short* xT   = wc + 1179648;                           // 4194304 (reused as xln)
  unsigned short* gbT  = xT + 4194304;                           // 1048576
  unsigned short* qkT  = gbT + 1048576;                          // 8388608
  unsigned short* vbuf = qkT + 8388608;                          // 4194304
  unsigned short* xpfT = vbuf + 4194304;                         // 4194304
  unsigned short* hT   = xpfT + 4194304;                         // 8388608

  hipMemsetAsync(stats, 0, 64 * sizeof(float), stream);

  cast_w<<<1152, 256, 0, stream>>>(qkvfw, qkvpw, fc1w, fc2w, wc);
  trans_x<<<dim3(4, 16, 16), 256, 0, stream>>>(x, xT);
  trans_gb<<<dim3(8, 16, 2), 256, 0, stream>>>(gamma, beta, gbT);

  gemm_mf<0, 256><<<dim3(6, 8, 16), 256, 0, stream>>>(
      wc, xT, qkT, vbuf, nullptr, nullptr, nullptr);

  attn_k<<<dim3(64, 16), 256, 0, stream>>>(qkT, vbuf, hrel, wrel, xpfT, stats);

  ln_k<<<2048, 256, 0, stream>>>(xpfT, gbT, stats, xT);   // xT reused as xln

  gemm_mf<1, 512><<<dim3(8, 8, 8), 256, 0, stream>>>(
      wc + 393216, xT, nullptr, nullptr, hT, nullptr, fc1b);

  gemm_mf<2, 1024><<<dim3(2, 8, 8), 256, 0, stream>>>(
      wc + 917504, hT, nullptr, nullptr, nullptr, out, fc2b);
}

// Round 5
// 245.927 us; speedup vs baseline: 1.5748x; 1.5748x over previous
//
#include <hip/hip_runtime.h>

#define SCALE 0.125f

typedef short short8 __attribute__((ext_vector_type(8)));
typedef float f32x4 __attribute__((ext_vector_type(4)));
typedef unsigned short us8 __attribute__((ext_vector_type(8)));

__device__ __forceinline__ unsigned short f2bf(float x) {
  unsigned int u = __float_as_uint(x);
  u += 0x7fff + ((u >> 16) & 1);
  return (unsigned short)(u >> 16);
}
__device__ __forceinline__ float bf2f(unsigned short b) {
  return __uint_as_float(((unsigned int)b) << 16);
}
__device__ __forceinline__ float gelu_exact(float x) {
  return 0.5f * x * (1.0f + erff(x * 0.70710678118654752f));
}

// ---------------------------------------------------------------------------
// Weight casts f32 -> bf16 (concatenated: qkvf | qkvp | fc1w | fc2w)
// ---------------------------------------------------------------------------
__global__ __launch_bounds__(256)
void cast_w(const float* __restrict__ qf, const float* __restrict__ qp,
            const float* __restrict__ f1, const float* __restrict__ f2,
            unsigned short* __restrict__ wc)
{
  const int i4 = (blockIdx.x * 256 + threadIdx.x) * 4;   // 1179648 total elems
  const float* src; int off;
  if (i4 < 196608)      { src = qf; off = i4; }
  else if (i4 < 393216) { src = qp; off = i4 - 196608; }
  else if (i4 < 917504) { src = f1; off = i4 - 393216; }
  else                  { src = f2; off = i4 - 917504; }
  const float4 v = *(const float4*)(src + off);
  ushort4 o;
  o.x = f2bf(v.x); o.y = f2bf(v.y); o.z = f2bf(v.z); o.w = f2bf(v.w);
  *(ushort4*)(wc + i4) = o;
}

// ---------------------------------------------------------------------------
// xT[z=(path*8+b)][tok 1024][ch 256] = bf16( x[b][path*256+ch][tok] )
// ---------------------------------------------------------------------------
__global__ __launch_bounds__(256)
void trans_x(const float* __restrict__ x, unsigned short* __restrict__ xT)
{
  __shared__ unsigned short L[64 * 72];
  const int ch0 = blockIdx.x * 64, tok0 = blockIdx.y * 64, z = blockIdx.z;
  const int b = z & 7, path = z >> 3;
  const float* src = x + (size_t)b * 524288 + (size_t)(path * 256 + ch0) * 1024 + tok0;
#pragma unroll
  for (int t = 0; t < 4; ++t) {
    const int i = threadIdx.x + t * 256;
    const int row = i >> 4, c4 = (i & 15) * 4;      // row = ch, c4 = tok
    const float4 v = *(const float4*)(src + (size_t)row * 1024 + c4);
    L[(c4 + 0) * 72 + row] = f2bf(v.x);
    L[(c4 + 1) * 72 + row] = f2bf(v.y);
    L[(c4 + 2) * 72 + row] = f2bf(v.z);
    L[(c4 + 3) * 72 + row] = f2bf(v.w);
  }
  __syncthreads();
  unsigned short* dst = xT + (size_t)z * 262144 + (size_t)tok0 * 256 + ch0;
#pragma unroll
  for (int t = 0; t < 2; ++t) {
    const int i = threadIdx.x + t * 256;
    const int row = i >> 3, c8 = (i & 7) * 8;       // row = tok, c8 = ch
    *(us8*)(dst + (size_t)row * 256 + c8) = *(const us8*)&L[row * 72 + c8];
  }
}

// ---------------------------------------------------------------------------
// gbT[which][tok 1024][ch 512] = bf16( {gamma,beta}[ch][tok] )
// ---------------------------------------------------------------------------
__global__ __launch_bounds__(256)
void trans_gb(const float* __restrict__ gamma, const float* __restrict__ beta,
              unsigned short* __restrict__ gbT)
{
  __shared__ unsigned short L[64 * 72];
  const int ch0 = blockIdx.x * 64, tok0 = blockIdx.y * 64, which = blockIdx.z;
  const float* src = (which ? beta : gamma) + (size_t)ch0 * 1024 + tok0;
#pragma unroll
  for (int t = 0; t < 4; ++t) {
    const int i = threadIdx.x + t * 256;
    const int row = i >> 4, c4 = (i & 15) * 4;
    const float4 v = *(const float4*)(src + (size_t)row * 1024 + c4);
    L[(c4 + 0) * 72 + row] = f2bf(v.x);
    L[(c4 + 1) * 72 + row] = f2bf(v.y);
    L[(c4 + 2) * 72 + row] = f2bf(v.z);
    L[(c4 + 3) * 72 + row] = f2bf(v.w);
  }
  __syncthreads();
  unsigned short* dst = gbT + (size_t)which * 524288 + (size_t)tok0 * 512 + ch0;
#pragma unroll
  for (int t = 0; t < 2; ++t) {
    const int i = threadIdx.x + t * 256;
    const int row = i >> 3, c8 = (i & 7) * 8;
    *(us8*)(dst + (size_t)row * 512 + c8) = *(const us8*)&L[row * 72 + c8];
  }
}

// ---------------------------------------------------------------------------
// MFMA GEMM: C[M][N] = A[M][K] @ B[N][K]^T, A/B bf16 k-contiguous.
// 128x128 block tile, 4 waves (2x2) of 64x64. Reg-staged double-buffered LDS,
// one barrier per k32 step. LDS rows unpadded (32 bf16) + XOR chunk swizzle.
// MODE 0: qkv -> qkT[z][tok][512] (m<512, transposed) + vbuf[z][ch][tok]
// MODE 1: fc1 -> bias+gelu -> hT[z][tok][1024] bf16 (transposed)
// MODE 2: fc2 -> bias -> out[z][oc][tok] f32
// ---------------------------------------------------------------------------
template<int MODE, int K>
__global__ __launch_bounds__(256, 3)
void gemm_mf(const unsigned short* __restrict__ A0, const unsigned short* __restrict__ B0,
             unsigned short* __restrict__ qkT, unsigned short* __restrict__ vb,
             unsigned short* __restrict__ hT, float* __restrict__ outF,
             const float* __restrict__ bias)
{
  __shared__ unsigned short As[2][4096];
  __shared__ unsigned short Bs[2][4096];
  const int tid = threadIdx.x;
  const int lane = tid & 63, w = tid >> 6;
  const int c = lane & 15, g = lane >> 4;
  const int wm = w >> 1, wn = w & 1;
  const int m0 = blockIdx.x * 128, n0 = blockIdx.y * 128;
  const int z = blockIdx.z;

  const unsigned short* A;
  const unsigned short* B;
  if (MODE == 0) {
    A = A0 + (size_t)(z >> 3) * 196608;
    B = B0 + (size_t)z * 262144;
  } else {
    A = A0;
    B = B0 + (size_t)z * 1024 * K;
  }

  f32x4 acc[4][4];
#pragma unroll
  for (int mi = 0; mi < 4; ++mi)
#pragma unroll
    for (int ni = 0; ni < 4; ++ni) acc[mi][ni] = (f32x4){0.f, 0.f, 0.f, 0.f};

  us8 a_r[2], b_r[2];
#pragma unroll
  for (int t = 0; t < 2; ++t) {
    const int i = tid + t * 256;
    const int row = i >> 2, kc = (i & 3) * 8;
    a_r[t] = *(const us8*)(A + (size_t)(m0 + row) * K + kc);
    b_r[t] = *(const us8*)(B + (size_t)(n0 + row) * K + kc);
  }

  int buf = 0;
  const int NK = K / 32;
  for (int ks = 0; ks < NK; ++ks) {
#pragma unroll
    for (int t = 0; t < 2; ++t) {
      const int i = tid + t * 256;
      const int row = i >> 2, kc = i & 3;
      const int p = row * 32 + ((kc ^ (row & 3)) * 8);
      *(us8*)&As[buf][p] = a_r[t];
      *(us8*)&Bs[buf][p] = b_r[t];
    }
    __syncthreads();
    if (ks + 1 < NK) {
      const int k0 = (ks + 1) * 32;
#pragma unroll
      for (int t = 0; t < 2; ++t) {
        const int i = tid + t * 256;
        const int row = i >> 2, kc = (i & 3) * 8;
        a_r[t] = *(const us8*)(A + (size_t)(m0 + row) * K + k0 + kc);
        b_r[t] = *(const us8*)(B + (size_t)(n0 + row) * K + k0 + kc);
      }
    }
    short8 aF[4], bF[4];
#pragma unroll
    for (int mi = 0; mi < 4; ++mi) {
      const int row = 64 * wm + 16 * mi + c;
      aF[mi] = *(const short8*)&As[buf][row * 32 + ((g ^ (row & 3)) * 8)];
    }
#pragma unroll
    for (int ni = 0; ni < 4; ++ni) {
      const int row = 64 * wn + 16 * ni + c;
      bF[ni] = *(const short8*)&Bs[buf][row * 32 + ((g ^ (row & 3)) * 8)];
    }
#pragma unroll
    for (int mi = 0; mi < 4; ++mi)
#pragma unroll
      for (int ni = 0; ni < 4; ++ni)
        acc[mi][ni] = __builtin_amdgcn_mfma_f32_16x16x32_bf16(aF[mi], bF[ni], acc[mi][ni], 0, 0, 0);
    buf ^= 1;
  }

  if (MODE == 0) {
#pragma unroll
    for (int mi = 0; mi < 4; ++mi) {
      const int mb = m0 + 64 * wm + 16 * mi + 4 * g;
#pragma unroll
      for (int ni = 0; ni < 4; ++ni) {
        const int n = n0 + 64 * wn + 16 * ni + c;
        if (mb < 512) {
          ushort4 o4;
          o4.x = f2bf(acc[mi][ni][0]); o4.y = f2bf(acc[mi][ni][1]);
          o4.z = f2bf(acc[mi][ni][2]); o4.w = f2bf(acc[mi][ni][3]);
          *(ushort4*)(qkT + (size_t)z * 524288 + (size_t)n * 512 + mb) = o4;
        } else {
#pragma unroll
          for (int r = 0; r < 4; ++r)
            vb[(size_t)z * 262144 + (size_t)(mb - 512 + r) * 1024 + n] = f2bf(acc[mi][ni][r]);
        }
      }
    }
  } else if (MODE == 1) {
#pragma unroll
    for (int mi = 0; mi < 4; ++mi) {
      const int mb = m0 + 64 * wm + 16 * mi + 4 * g;
      const float4 b4 = *(const float4*)(bias + mb);
#pragma unroll
      for (int ni = 0; ni < 4; ++ni) {
        const int n = n0 + 64 * wn + 16 * ni + c;
        ushort4 o4;
        o4.x = f2bf(gelu_exact(acc[mi][ni][0] + b4.x));
        o4.y = f2bf(gelu_exact(acc[mi][ni][1] + b4.y));
        o4.z = f2bf(gelu_exact(acc[mi][ni][2] + b4.z));
        o4.w = f2bf(gelu_exact(acc[mi][ni][3] + b4.w));
        *(ushort4*)(hT + (size_t)z * 1048576 + (size_t)n * 1024 + mb) = o4;
      }
    }
  } else {
#pragma unroll
    for (int mi = 0; mi < 4; ++mi) {
      const int mb = m0 + 64 * wm + 16 * mi + 4 * g;
      const float4 b4 = *(const float4*)(bias + mb);
#pragma unroll
      for (int ni = 0; ni < 4; ++ni) {
        const int n = n0 + 64 * wn + 16 * ni + c;
        float* op = outF + (size_t)z * 262144 + (size_t)mb * 1024 + n;
        op[0]    = acc[mi][ni][0] + b4.x;
        op[1024] = acc[mi][ni][1] + b4.y;
        op[2048] = acc[mi][ni][2] + b4.z;
        op[3072] = acc[mi][ni][3] + b4.w;
      }
    }
  }
}

// ---------------------------------------------------------------------------
// MFMA flash attention v3: LDS-traffic-minimized.
// Block = 128 q-rows of one (path,b,head); 4 waves x 32 q-rows (2 groups).
// S computed transposed (A=K, B=Q): K/V LDS fragments are reused by BOTH
// q-groups (halves LDS reads per MFMA); P packs as ds_write_b64; qw lives in
// 16 regs; qh = 4 b16 reads/iter. K/V double-buffered in LDS, 1 barrier/iter,
// next tile prefetched into registers. XOR-swizzled unpadded tiles.
// Grid: x = pbh (64) -> blocks sharing K/V land on one XCD; y = q-eighth.
// ---------------------------------------------------------------------------
__global__ __launch_bounds__(256, 2)
void attn_k(const unsigned short* __restrict__ qkT,  // [16][1024][512] bf16
            const unsigned short* __restrict__ vbuf, // [16][256][1024] bf16
            const float* __restrict__ hrel,          // [63][64] f32
            const float* __restrict__ wrel,          // [63][64] f32
            unsigned short* __restrict__ xpfT,       // [8][1024][512] bf16
            float* __restrict__ stats)               // [8][2] f32
{
  __shared__ unsigned short Kb[2][4096];   // K tile [key][d], swizzled
  __shared__ unsigned short Vb[2][4096];   // V tile [d][key], swizzled
  __shared__ unsigned short Ps[128 * 72];  // QW table / P tile / Out stage
  __shared__ unsigned short QHt[128 * 34]; // qh[row][h2], h2 in [0,32)

  const int tid = threadIdx.x;
  const int lane = tid & 63, w = tid >> 6;
  const int c = lane & 15, g = lane >> 4;
  const int xb = blockIdx.x;
  const int pOut = xb >> 5, bh = xb & 31;
  const int b = bh >> 2, head = bh & 3, pKV = 1 - pOut;
  const int n0 = blockIdx.y * 128;
  const int rb = 32 * w;

  const unsigned short* Qg = qkT + (size_t)(pOut * 8 + b) * 524288 + head * 64;
  const unsigned short* Kg = qkT + (size_t)(pKV * 8 + b) * 524288 + 256 + head * 64;
  const unsigned short* Vg = vbuf + ((size_t)(pKV * 8 + b) * 256 + head * 64) * 1024;

  // ---- issue tile-0 staging loads first (latency hidden behind prologue)
  us8 kr[2], vr[2];
#pragma unroll
  for (int t = 0; t < 2; ++t) {
    const int i = tid + t * 256;
    const int row = i >> 3, ch = i & 7;
    kr[t] = *(const us8*)(Kg + (size_t)row * 512 + ch * 8);
    vr[t] = *(const us8*)(Vg + (size_t)row * 1024 + ch * 8);
  }

  // ---- Q B-fragments for the wave's 2 row-groups (resident all kernel)
  short8 bQ[2][2];
#pragma unroll
  for (int grp = 0; grp < 2; ++grp) {
    const unsigned short* qp = Qg + (size_t)(n0 + rb + 16 * grp + c) * 512 + 8 * g;
    bQ[grp][0] = *(const short8*)(qp);
    bQ[grp][1] = *(const short8*)(qp + 32);
  }

  // ---- prologue: QW/QH via MFMA (A=rel rows, B=Q). Wave-private LDS rows.
#pragma unroll
  for (int f = 0; f < 4; ++f) {
    const int rr = 16 * f + c;
    const int rrc = rr < 63 ? rr : 62;
    const float sc = rr < 63 ? 1.f : 0.f;
    short8 w0, w1, h0, h1;
#pragma unroll
    for (int j = 0; j < 8; ++j) {
      w0[j] = f2bf(wrel[rrc * 64 + 8 * g + j] * sc);
      w1[j] = f2bf(wrel[rrc * 64 + 32 + 8 * g + j] * sc);
      h0[j] = f2bf(hrel[rrc * 64 + 8 * g + j] * sc);
      h1[j] = f2bf(hrel[rrc * 64 + 32 + 8 * g + j] * sc);
    }
#pragma unroll
    for (int grp = 0; grp < 2; ++grp) {
      f32x4 zw = {0.f, 0.f, 0.f, 0.f};
      zw = __builtin_amdgcn_mfma_f32_16x16x32_bf16(w0, bQ[grp][0], zw, 0, 0, 0);
      zw = __builtin_amdgcn_mfma_f32_16x16x32_bf16(w1, bQ[grp][1], zw, 0, 0, 0);
      f32x4 zh = {0.f, 0.f, 0.f, 0.f};
      zh = __builtin_amdgcn_mfma_f32_16x16x32_bf16(h0, bQ[grp][0], zh, 0, 0, 0);
      zh = __builtin_amdgcn_mfma_f32_16x16x32_bf16(h1, bQ[grp][1], zh, 0, 0, 0);
      const int qrow = rb + 16 * grp + c;          // lane's own q-row
      ushort4 pw;
      pw.x = f2bf(zw[0]); pw.y = f2bf(zw[1]); pw.z = f2bf(zw[2]); pw.w = f2bf(zw[3]);
      *(ushort4*)&Ps[qrow * 72 + 16 * f + 4 * g] = pw;   // QW[qrow][rw]
      const int h1i = (n0 + qrow) >> 5;
#pragma unroll
      for (int r = 0; r < 4; ++r) {
        const int h2 = 16 * f + 4 * g + r - 31 + h1i;
        if (h2 >= 0 && h2 < 32) QHt[qrow * 34 + h2] = f2bf(zh[r]);
      }
    }
  }

  // read back the 16 loop-invariant qw values (wave-private rows, in-order LDS)
  float qwv[2][2][4];
#pragma unroll
  for (int grp = 0; grp < 2; ++grp) {
    const int qrow = rb + 16 * grp + c;
    const int w1i = (n0 + qrow) & 31;
#pragma unroll
    for (int p = 0; p < 2; ++p)
#pragma unroll
      for (int r = 0; r < 4; ++r)
        qwv[grp][p][r] = bf2f(Ps[qrow * 72 + (16 * p + 4 * g + r - w1i + 31)]);
  }

  // write tile 0 to buffer 0
#pragma unroll
  for (int t = 0; t < 2; ++t) {
    const int i = tid + t * 256;
    const int row = i >> 3, ch = i & 7;
    const int p = row * 64 + ((ch ^ (row & 7)) * 8);
    *(us8*)&Kb[0][p] = kr[t];
    *(us8*)&Vb[0][p] = vr[t];
  }

  float lsum[2] = {0.f, 0.f};
  f32x4 O[2][4];
#pragma unroll
  for (int grp = 0; grp < 2; ++grp)
#pragma unroll
    for (int f = 0; f < 4; ++f) O[grp][f] = (f32x4){0.f, 0.f, 0.f, 0.f};

  for (int mt = 0; mt < 16; ++mt) {
    if (mt < 15) {
      const int m0n = (mt + 1) * 64;
#pragma unroll
      for (int t = 0; t < 2; ++t) {
        const int i = tid + t * 256;
        const int row = i >> 3, ch = i & 7;
        kr[t] = *(const us8*)(Kg + (size_t)(m0n + row) * 512 + ch * 8);
        vr[t] = *(const us8*)(Vg + (size_t)row * 1024 + m0n + ch * 8);
      }
    }
    __syncthreads();   // current buffer staged & all prior-tile reads done
    const unsigned short* Ks = Kb[mt & 1];
    const unsigned short* Vs = Vb[mt & 1];

    // K fragments (shared by both q-groups)
    short8 kA[4][2];
#pragma unroll
    for (int f = 0; f < 4; ++f) {
      const int row = 16 * f + c;
      kA[f][0] = *(const short8*)&Ks[row * 64 + ((g ^ (row & 7)) * 8)];
      kA[f][1] = *(const short8*)&Ks[row * 64 + (((4 + g) ^ (row & 7)) * 8)];
    }
    // S^T = K Q^T, softmax, P -> LDS (wave-private rows, b64 packs)
#pragma unroll
    for (int grp = 0; grp < 2; ++grp) {
      const int qrow = rb + 16 * grp + c;
      const float qh0 = bf2f(QHt[qrow * 34 + 2 * mt]);
      const float qh1 = bf2f(QHt[qrow * 34 + 2 * mt + 1]);
#pragma unroll
      for (int f = 0; f < 4; ++f) {
        f32x4 z = {0.f, 0.f, 0.f, 0.f};
        z = __builtin_amdgcn_mfma_f32_16x16x32_bf16(kA[f][0], bQ[grp][0], z, 0, 0, 0);
        z = __builtin_amdgcn_mfma_f32_16x16x32_bf16(kA[f][1], bQ[grp][1], z, 0, 0, 0);
        const float qh = (f >= 2) ? qh1 : qh0;
        const float* qwp = qwv[grp][f & 1];
        const float p0 = __expf(fmaf(z[0], SCALE, qh + qwp[0]));
        const float p1 = __expf(fmaf(z[1], SCALE, qh + qwp[1]));
        const float p2 = __expf(fmaf(z[2], SCALE, qh + qwp[2]));
        const float p3 = __expf(fmaf(z[3], SCALE, qh + qwp[3]));
        lsum[grp] += (p0 + p1) + (p2 + p3);
        ushort4 pk;
        pk.x = f2bf(p0); pk.y = f2bf(p1); pk.z = f2bf(p2); pk.w = f2bf(p3);
        *(ushort4*)&Ps[qrow * 72 + 16 * f + 4 * g] = pk;
      }
    }
    // V fragments (shared by both q-groups)
    short8 vB[4][2];
#pragma unroll
    for (int f = 0; f < 4; ++f) {
      const int row = 16 * f + c;
      vB[f][0] = *(const short8*)&Vs[row * 64 + ((g ^ (row & 7)) * 8)];
      vB[f][1] = *(const short8*)&Vs[row * 64 + (((4 + g) ^ (row & 7)) * 8)];
    }
    // O += P V  (A=P from wave-private LDS rows, in-wave ordering)
#pragma unroll
    for (int grp = 0; grp < 2; ++grp) {
      const int qrow = rb + 16 * grp + c;
      const short8 aP0 = *(const short8*)&Ps[qrow * 72 + 8 * g];
      const short8 aP1 = *(const short8*)&Ps[qrow * 72 + 32 + 8 * g];
#pragma unroll
      for (int f = 0; f < 4; ++f) {
        O[grp][f] = __builtin_amdgcn_mfma_f32_16x16x32_bf16(aP0, vB[f][0], O[grp][f], 0, 0, 0);
        O[grp][f] = __builtin_amdgcn_mfma_f32_16x16x32_bf16(aP1, vB[f][1], O[grp][f], 0, 0, 0);
      }
    }
    // stage next tile into the other buffer (safe: all waves passed barrier)
    if (mt < 15) {
#pragma unroll
      for (int t = 0; t < 2; ++t) {
        const int i = tid + t * 256;
        const int row = i >> 3, ch = i & 7;
        const int p = row * 64 + ((ch ^ (row & 7)) * 8);
        *(us8*)&Kb[(mt + 1) & 1][p] = kr[t];
        *(us8*)&Vb[(mt + 1) & 1][p] = vr[t];
      }
    }
  }

  // row sums (reduce over g), then per-O-row inverse
#pragma unroll
  for (int grp = 0; grp < 2; ++grp) {
    lsum[grp] += __shfl_xor(lsum[grp], 16);
    lsum[grp] += __shfl_xor(lsum[grp], 32);
  }
  float linv[2][4];
#pragma unroll
  for (int grp = 0; grp < 2; ++grp)
#pragma unroll
    for (int r = 0; r < 4; ++r)
      linv[grp][r] = 1.0f / __shfl(lsum[grp], 4 * g + r);

  float ssum = 0.f, ssq = 0.f;
#pragma unroll
  for (int grp = 0; grp < 2; ++grp)
#pragma unroll
    for (int f = 0; f < 4; ++f)
#pragma unroll
      for (int r = 0; r < 4; ++r) {
        const float v = O[grp][f][r] * linv[grp][r];
        ssum += v;
        ssq = fmaf(v, v, ssq);
        Ps[(rb + 16 * grp + 4 * g + r) * 72 + 16 * f + c] = f2bf(v);  // Out[row][d]
      }
#pragma unroll
  for (int off = 1; off < 64; off <<= 1) {
    ssum += __shfl_xor(ssum, off);
    ssq  += __shfl_xor(ssq, off);
  }
  if (lane == 0) {
    atomicAdd(&stats[b * 2 + 0], ssum);
    atomicAdd(&stats[b * 2 + 1], ssq);
  }

  __syncthreads();
  unsigned short* dst = xpfT + ((size_t)b * 1024 + n0) * 512 + pOut * 256 + head * 64;
#pragma unroll
  for (int t = 0; t < 4; ++t) {
    const int i = tid + t * 256;
    const int row = i >> 3, ch = i & 7;
    *(us8*)(dst + (size_t)row * 512 + ch * 8) = *(const us8*)&Ps[row * 72 + ch * 8];
  }
}

// ---------------------------------------------------------------------------
// LayerNorm apply: xln[b][tok][512] = (xpfT - mean)*rstd*gammaT + betaT (bf16)
// ---------------------------------------------------------------------------
__global__ __launch_bounds__(256)
void ln_k(const unsigned short* __restrict__ xpfT, const unsigned short* __restrict__ gbT,
          const float* __restrict__ stats, unsigned short* __restrict__ xln)
{
  const int i = blockIdx.x * 256 + threadIdx.x;   // us8 chunk index, 524288 total
  const int b = i >> 16, off = i & 65535;
  const float invN = 1.0f / 524288.0f;
  const float mean = stats[b * 2] * invN;
  const float var = stats[b * 2 + 1] * invN - mean * mean;
  const float rstd = rsqrtf(var + 1e-5f);
  const us8 xv = *(const us8*)(xpfT + (size_t)i * 8);
  const us8 gv = *(const us8*)(gbT + (size_t)off * 8);
  const us8 bv = *(const us8*)(gbT + 524288 + (size_t)off * 8);
  us8 ov;
#pragma unroll
  for (int j = 0; j < 8; ++j)
    ov[j] = f2bf((bf2f(xv[j]) - mean) * rstd * bf2f(gv[j]) + bf2f(bv[j]));
  *(us8*)(xln + (size_t)i * 8) = ov;
}

// ---------------------------------------------------------------------------
extern "C" void kernel_launch(void* const* d_in, const int* in_sizes, int n_in,
                              void* d_out, int out_size, void* d_ws, size_t ws_size,
                              hipStream_t stream)
{
  const float* x     = (const float*)d_in[0];
  const float* qkvfw = (const float*)d_in[1];
  const float* qkvpw = (const float*)d_in[2];
  const float* hrel  = (const float*)d_in[3];
  const float* wrel  = (const float*)d_in[4];
  const float* gamma = (const float*)d_in[5];
  const float* beta  = (const float*)d_in[6];
  const float* fc1w  = (const float*)d_in[7];
  const float* fc1b  = (const float*)d_in[8];
  const float* fc2w  = (const float*)d_in[9];
  const float* fc2b  = (const float*)d_in[10];
  float* out = (float*)d_out;

  // ws layout (bf16 elements unless noted), ~63.4 MB total
  float* stats = (float*)d_ws;                                   // 64 f32
  unsigned short* wc   = (unsigned short*)(stats + 64);          // 1179648
  unsigned short* xT   = wc + 1179648;                           // 4194304 (reused as xln)
  unsigned short* gbT  = xT + 4194304;                           // 1048576
  unsigned short* qkT  = gbT + 1048576;                          // 8388608
  unsigned short* vbuf = qkT + 8388608;                          // 4194304
  unsigned short* xpfT = vbuf + 4194304;                         // 4194304
  unsigned short* hT   = xpfT + 4194304;                         // 8388608

  hipMemsetAsync(stats, 0, 64 * sizeof(float), stream);

  cast_w<<<1152, 256, 0, stream>>>(qkvfw, qkvpw, fc1w, fc2w, wc);
  trans_x<<<dim3(4, 16, 16), 256, 0, stream>>>(x, xT);
  trans_gb<<<dim3(8, 16, 2), 256, 0, stream>>>(gamma, beta, gbT);

  gemm_mf<0, 256><<<dim3(6, 8, 16), 256, 0, stream>>>(
      wc, xT, qkT, vbuf, nullptr, nullptr, nullptr);

  attn_k<<<dim3(64, 8), 256, 0, stream>>>(qkT, vbuf, hrel, wrel, xpfT, stats);

  ln_k<<<2048, 256, 0, stream>>>(xpfT, gbT, stats, xT);   // xT reused as xln

  gemm_mf<1, 512><<<dim3(8, 8, 8), 256, 0, stream>>>(
      wc + 393216, xT, nullptr, nullptr, hT, nullptr, fc1b);

  gemm_mf<2, 1024><<<dim3(2, 8, 8), 256, 0, stream>>>(
      wc + 917504, hT, nullptr, nullptr, nullptr, out, fc2b);
}